// Round 6
// baseline (197.607 us; speedup 1.0000x reference)
//
#include <hip/hip_runtime.h>
#include <hip/hip_bf16.h>
#include <stdint.h>
#include <stddef.h>

typedef __bf16 bf16;
typedef float f32x4 __attribute__((ext_vector_type(4)));
typedef bf16 bf16x8 __attribute__((ext_vector_type(8)));
typedef bf16 bf16x4 __attribute__((ext_vector_type(4)));

#define MROWS 8192
#define NOUT 256
#define BM 32
#define BK 128
#define NTHREADS 512

#define LDS_A_BYTES (BM * BK * 2)  // 8 KiB bf16 A tile per slot

#define SCHED0 __builtin_amdgcn_sched_barrier(0)
#define SBAR __builtin_amdgcn_s_barrier()

// ---------------------------------------------------------------------------
// Bp fragment-permuted layout: for K-step ts, wave w, frag (bfi,ak), lane l,
// 16-byte lane chunk at byte offset (ts*64 + w*8 + bfi*4 + ak)*1024 + l*16,
// holding B[n][k0..k0+7], n = w*32+bfi*16+(l&15), k0 = ts*128+ak*32+(l>>4)*8.
// Producer map for (n,k): ts=k>>7, w=n>>5, bfi=(n>>4)&1, ak=(k>>5)&3,
//   l=((k>>3)&3)*16+(n&15), byte=(k&7)*2.
// ---------------------------------------------------------------------------

// ============== deep-pipelined kernel (NT%4==0, NT>=8) ======================
// Invariants at top of step t:
//   slots: slot[s&3] holds A(s) for s in {t, t+1} (written at s-2)
//   f-regs: afr(t) (ds_read at t-1);  B-regs: B(t) (loaded at t-1)
//   g-sets: A(t+2) (loaded t-3), A(t+3) (t-2), A(t+4) (t-1)
// Step t: load B(t+1); load A(t+5)->gset[(t+1)&3]; ds_write A(t+2) from
//   gset[(t+2)&3] (3 steps of HBM latency slack); ds_read afr(t+1);
//   MFMA afr(t) x B(t); lgkm drain; barrier.
template <bool SCALE, bool OUTT>
__global__ __launch_bounds__(NTHREADS, 1) void gemm_deep(
    const float* __restrict__ A, const bf16* __restrict__ Bp,
    const float* __restrict__ filt, void* __restrict__ outp,
    const int K, const int lda) {
  __shared__ char lds[4][LDS_A_BYTES];
  const int t = threadIdx.x;
  const int w = t >> 6;
  const int l = t & 63;
  const int m0 = blockIdx.x * BM;
  const int NT = K / BK;

  const int ar = t >> 4;
  const int acb = t & 15;
  const float* gA = A + (size_t)(m0 + ar) * (size_t)lda + acb * 8;
  const int a_lds_off = (ar * (BK * 2) + acb * 16) ^ ((ar & 7) << 4);

  int aoff[2][4];
#pragma unroll
  for (int af = 0; af < 2; ++af)
#pragma unroll
    for (int ak = 0; ak < 4; ++ak) {
      const int r = af * 16 + (l & 15);
      const int kb = ak * 64 + (l >> 4) * 16;
      aoff[af][ak] = (r * (BK * 2) + kb) ^ ((r & 7) << 4);
    }

  const char* pBw = (const char*)Bp + w * 8192 + l * 16;

  f32x4 acc[2][2] = {};

  // ---------------- prologue ----------------
  f32x4 g0a = __builtin_nontemporal_load((const f32x4*)gA);
  f32x4 g0b = __builtin_nontemporal_load((const f32x4*)gA + 1);
  f32x4 g1a = __builtin_nontemporal_load((const f32x4*)(gA + BK));
  f32x4 g1b = __builtin_nontemporal_load((const f32x4*)(gA + BK) + 1);
  f32x4 g2a = __builtin_nontemporal_load((const f32x4*)(gA + 2 * BK));
  f32x4 g2b = __builtin_nontemporal_load((const f32x4*)(gA + 2 * BK) + 1);
  f32x4 g3a = __builtin_nontemporal_load((const f32x4*)(gA + 3 * BK));
  f32x4 g3b = __builtin_nontemporal_load((const f32x4*)(gA + 3 * BK) + 1);
  bf16x8 Ba[2][4], Bb[2][4];
#pragma unroll
  for (int bfi = 0; bfi < 2; ++bfi)
#pragma unroll
    for (int ak = 0; ak < 4; ++ak)
      Ba[bfi][ak] = *(const bf16x8*)(pBw + (bfi * 4 + ak) * 1024);
  {
    bf16x8 pk;
#pragma unroll
    for (int j = 0; j < 4; ++j) { pk[j] = (bf16)g0a[j]; pk[j + 4] = (bf16)g0b[j]; }
    *(bf16x8*)(lds[0] + a_lds_off) = pk;
  }
  // reuse g0 for A(4) (WAR dep on the cvt above keeps order)
  g0a = __builtin_nontemporal_load((const f32x4*)(gA + 4 * BK));
  g0b = __builtin_nontemporal_load((const f32x4*)(gA + 4 * BK) + 1);
  {
    bf16x8 pk;
#pragma unroll
    for (int j = 0; j < 4; ++j) { pk[j] = (bf16)g1a[j]; pk[j + 4] = (bf16)g1b[j]; }
    *(bf16x8*)(lds[1] + a_lds_off) = pk;
  }
  asm volatile("s_waitcnt lgkmcnt(0)" ::: "memory");
  SBAR;
  SCHED0;
  bf16x8 fa[2][4], fb[2][4];
#pragma unroll
  for (int af = 0; af < 2; ++af)
#pragma unroll
    for (int ak = 0; ak < 4; ++ak)
      fa[af][ak] = *(const bf16x8*)(lds[0] + aoff[af][ak]);
  SCHED0;

  // BODY(TS, SW, SR, FC, FN, BC, BN, GW=A(TS+2) regs, GL=regs for A(TS+5))
#define BODY_D(TS, SW, SR, FC, FN, BC, BN, GWa, GWb, GLa, GLb)                \
  {                                                                           \
    const size_t kb1 = (size_t)((((TS) + 1) < NT ? ((TS) + 1) : 0)) << 16;    \
    _Pragma("unroll") for (int bfi = 0; bfi < 2; ++bfi)                       \
        _Pragma("unroll") for (int ak = 0; ak < 4; ++ak)                      \
            BN[bfi][ak] =                                                     \
                *(const bf16x8*)(pBw + kb1 + (bfi * 4 + ak) * 1024);          \
    SCHED0;                                                                   \
    const int ka5 = ((((TS) + 5) < NT) ? ((TS) + 5) : 0) * BK;                \
    GLa = __builtin_nontemporal_load((const f32x4*)(gA + ka5));               \
    GLb = __builtin_nontemporal_load((const f32x4*)(gA + ka5) + 1);           \
    SCHED0;                                                                   \
    {                                                                         \
      bf16x8 pk;                                                              \
      _Pragma("unroll") for (int j = 0; j < 4; ++j) {                         \
        pk[j] = (bf16)GWa[j];                                                 \
        pk[j + 4] = (bf16)GWb[j];                                             \
      }                                                                       \
      *(bf16x8*)(lds[SW] + a_lds_off) = pk;                                   \
    }                                                                         \
    SCHED0;                                                                   \
    _Pragma("unroll") for (int af = 0; af < 2; ++af)                          \
        _Pragma("unroll") for (int ak = 0; ak < 4; ++ak)                      \
            FN[af][ak] = *(const bf16x8*)(lds[SR] + aoff[af][ak]);            \
    SCHED0;                                                                   \
    __builtin_amdgcn_s_setprio(1);                                            \
    _Pragma("unroll") for (int ak = 0; ak < 4; ++ak)                          \
        _Pragma("unroll") for (int af = 0; af < 2; ++af)                      \
            _Pragma("unroll") for (int bfi = 0; bfi < 2; ++bfi)               \
                acc[af][bfi] = __builtin_amdgcn_mfma_f32_16x16x32_bf16(       \
                    FC[af][ak], BC[bfi][ak], acc[af][bfi], 0, 0, 0);          \
    __builtin_amdgcn_s_setprio(0);                                            \
    SCHED0;                                                                   \
    asm volatile("s_waitcnt lgkmcnt(0)" ::: "memory");                        \
    SBAR;                                                                     \
    SCHED0;                                                                   \
  }

  for (int ts = 0; ts < NT; ts += 4) {
    BODY_D(ts,     2, 1, fa, fb, Ba, Bb, g2a, g2b, g1a, g1b);
    BODY_D(ts + 1, 3, 2, fb, fa, Bb, Ba, g3a, g3b, g2a, g2b);
    BODY_D(ts + 2, 0, 3, fa, fb, Ba, Bb, g0a, g0b, g3a, g3b);
    BODY_D(ts + 3, 1, 0, fb, fa, Bb, Ba, g1a, g1b, g0a, g0b);
  }
#undef BODY_D

  // ---- epilogue (C/D: col = lane&15, row = (lane>>4)*4 + reg)
#pragma unroll
  for (int af = 0; af < 2; ++af)
#pragma unroll
    for (int bfi = 0; bfi < 2; ++bfi) {
      const int mb = m0 + af * 16 + (l >> 4) * 4;
      const int n = w * 32 + bfi * 16 + (l & 15);
      f32x4 v = acc[af][bfi];
      if (SCALE) {
#pragma unroll
        for (int j = 0; j < 4; ++j) v[j] *= filt[mb + j];
      }
      if (OUTT) {
        bf16x4 pv;
#pragma unroll
        for (int j = 0; j < 4; ++j) pv[j] = (bf16)v[j];
        const int tsq = mb >> 7, wq = n >> 5, bq = (n >> 4) & 1, aq = (mb >> 5) & 3;
        const int lq = ((mb >> 3) & 3) * 16 + (n & 15);
        char* dst = (char*)outp +
                    (size_t)(((tsq * 64 + wq * 8 + bq * 4 + aq) << 10) + lq * 16 +
                             (mb & 7) * 2);
        *(bf16x4*)dst = pv;
      } else {
        float* po = (float*)outp + (size_t)mb * NOUT + n;
#pragma unroll
        for (int j = 0; j < 4; ++j) po[(size_t)j * NOUT] = v[j];
      }
    }
}

// ======================= small-K kernel (round-4 schedule, NT>=2) ===========
template <bool SCALE, bool OUTT>
__global__ __launch_bounds__(NTHREADS, 1) void gemm_small(
    const float* __restrict__ A, const bf16* __restrict__ Bp,
    const float* __restrict__ filt, void* __restrict__ outp,
    const int K, const int lda) {
  __shared__ char lds[2][LDS_A_BYTES];
  const int t = threadIdx.x;
  const int w = t >> 6;
  const int l = t & 63;
  const int m0 = blockIdx.x * BM;
  const int NT = K / BK;

  const int ar = t >> 4;
  const int acb = t & 15;
  const float* gA = A + (size_t)(m0 + ar) * (size_t)lda + acb * 8;
  const int a_lds_off = (ar * (BK * 2) + acb * 16) ^ ((ar & 7) << 4);

  int aoff[2][4];
#pragma unroll
  for (int af = 0; af < 2; ++af)
#pragma unroll
    for (int ak = 0; ak < 4; ++ak) {
      const int r = af * 16 + (l & 15);
      const int kb = ak * 64 + (l >> 4) * 16;
      aoff[af][ak] = (r * (BK * 2) + kb) ^ ((r & 7) << 4);
    }

  const char* pBw = (const char*)Bp + w * 8192 + l * 16;

  f32x4 acc[2][2] = {};

  f32x4 aS0a = __builtin_nontemporal_load((const f32x4*)gA);
  f32x4 aS0b = __builtin_nontemporal_load((const f32x4*)gA + 1);
  f32x4 aS1a = __builtin_nontemporal_load((const f32x4*)(gA + BK));
  f32x4 aS1b = __builtin_nontemporal_load((const f32x4*)(gA + BK) + 1);
  bf16x8 Bc[2][4], Bn[2][4];
#pragma unroll
  for (int bfi = 0; bfi < 2; ++bfi)
#pragma unroll
    for (int ak = 0; ak < 4; ++ak)
      Bc[bfi][ak] = *(const bf16x8*)(pBw + (bfi * 4 + ak) * 1024);
  {
    bf16x8 pk;
#pragma unroll
    for (int j = 0; j < 4; ++j) { pk[j] = (bf16)aS0a[j]; pk[j + 4] = (bf16)aS0b[j]; }
    *(bf16x8*)(lds[0] + a_lds_off) = pk;
  }
  asm volatile("s_waitcnt lgkmcnt(0)" ::: "memory");
  SBAR;
  SCHED0;

#define BODY_S(TS, P, BCUR, BNXT, AW0, AW1, AL0, AL1)                         \
  {                                                                           \
    const char* bb = lds[P];                                                  \
    bf16x8 afr[2][4];                                                         \
    _Pragma("unroll") for (int af = 0; af < 2; ++af)                          \
        _Pragma("unroll") for (int ak = 0; ak < 4; ++ak)                      \
            afr[af][ak] = *(const bf16x8*)(bb + aoff[af][ak]);                \
    SCHED0;                                                                   \
    const size_t kb1 = (size_t)((((TS) + 1) < NT ? ((TS) + 1) : 0)) << 16;    \
    _Pragma("unroll") for (int bfi = 0; bfi < 2; ++bfi)                       \
        _Pragma("unroll") for (int ak = 0; ak < 4; ++ak)                      \
            BNXT[bfi][ak] =                                                   \
                *(const bf16x8*)(pBw + kb1 + (bfi * 4 + ak) * 1024);          \
    SCHED0;                                                                   \
    const int ka2 = (((TS) + 2) < NT ? ((TS) + 2) : 0) * BK;                  \
    AL0 = __builtin_nontemporal_load((const f32x4*)(gA + ka2));               \
    AL1 = __builtin_nontemporal_load((const f32x4*)(gA + ka2) + 1);           \
    SCHED0;                                                                   \
    asm volatile("s_waitcnt lgkmcnt(0)" ::: "memory");                        \
    SCHED0;                                                                   \
    __builtin_amdgcn_s_setprio(1);                                            \
    _Pragma("unroll") for (int ak = 0; ak < 4; ++ak)                          \
        _Pragma("unroll") for (int af = 0; af < 2; ++af)                      \
            _Pragma("unroll") for (int bfi = 0; bfi < 2; ++bfi)               \
                acc[af][bfi] = __builtin_amdgcn_mfma_f32_16x16x32_bf16(       \
                    afr[af][ak], BCUR[bfi][ak], acc[af][bfi], 0, 0, 0);       \
    __builtin_amdgcn_s_setprio(0);                                            \
    SCHED0;                                                                   \
    {                                                                         \
      bf16x8 pk;                                                              \
      _Pragma("unroll") for (int j = 0; j < 4; ++j) {                         \
        pk[j] = (bf16)AW0[j];                                                 \
        pk[j + 4] = (bf16)AW1[j];                                             \
      }                                                                       \
      *(bf16x8*)(lds[P ^ 1] + a_lds_off) = pk;                                \
    }                                                                         \
    asm volatile("s_waitcnt lgkmcnt(0)" ::: "memory");                        \
    SBAR;                                                                     \
    SCHED0;                                                                   \
  }

  for (int ts = 0; ts < NT; ts += 2) {
    BODY_S(ts, 0, Bc, Bn, aS1a, aS1b, aS0a, aS0b);
    BODY_S(ts + 1, 1, Bn, Bc, aS0a, aS0b, aS1a, aS1b);
  }
#undef BODY_S

#pragma unroll
  for (int af = 0; af < 2; ++af)
#pragma unroll
    for (int bfi = 0; bfi < 2; ++bfi) {
      const int mb = m0 + af * 16 + (l >> 4) * 4;
      const int n = w * 32 + bfi * 16 + (l & 15);
      f32x4 v = acc[af][bfi];
      if (SCALE) {
#pragma unroll
        for (int j = 0; j < 4; ++j) v[j] *= filt[mb + j];
      }
      if (OUTT) {
        bf16x4 pv;
#pragma unroll
        for (int j = 0; j < 4; ++j) pv[j] = (bf16)v[j];
        const int tsq = mb >> 7, wq = n >> 5, bq = (n >> 4) & 1, aq = (mb >> 5) & 3;
        const int lq = ((mb >> 3) & 3) * 16 + (n & 15);
        char* dst = (char*)outp +
                    (size_t)(((tsq * 64 + wq * 8 + bq * 4 + aq) << 10) + lq * 16 +
                             (mb & 7) * 2);
        *(bf16x4*)dst = pv;
      } else {
        float* po = (float*)outp + (size_t)mb * NOUT + n;
#pragma unroll
        for (int j = 0; j < 4; ++j) po[(size_t)j * NOUT] = v[j];
      }
    }
}

// W [256 k][256 n] fp32 -> Wp bf16 in Bp layout
__global__ void prep_wt(const float* __restrict__ W, bf16* __restrict__ Wp) {
  const int k = blockIdx.x;
  const int n = threadIdx.x;
  const int off = (((k >> 7) * 64 + (n >> 5) * 8 + ((n >> 4) & 1) * 4 +
                    ((k >> 5) & 3)) << 10) +
                  (((k >> 3) & 3) * 16 + (n & 15)) * 16 + (k & 7) * 2;
  *(bf16*)((char*)Wp + off) = (bf16)W[k * 256 + n];
}

extern "C" void kernel_launch(void* const* d_in, const int* in_sizes, int n_in,
                              void* d_out, int out_size, void* d_ws, size_t ws_size,
                              hipStream_t stream) {
  const float* features = (const float*)d_in[0];
  const float* wavelets = (const float*)d_in[1];
  const float* wavelets_inv = (const float*)d_in[2];
  const float* W = (const float*)d_in[3];
  const float* filt = (const float*)d_in[4];
  float* out = (float*)d_out;

  char* ws = (char*)d_ws;
  bf16* Wp = (bf16*)ws;                       // 128 KiB, Bp layout (K=256)
  bf16* Tp = (bf16*)(ws + 131072);            // 4 MiB, Bp layout (K=8192)
  bf16* Fp = (bf16*)(ws + 131072 + 4194304);  // 4 MiB, Bp layout (K=8192)

  prep_wt<<<256, 256, 0, stream>>>(W, Wp);
  gemm_small<false, true><<<256, NTHREADS, 0, stream>>>(features, Wp, nullptr, Tp, 256, 256);
  gemm_deep<true, true><<<256, NTHREADS, 0, stream>>>(wavelets_inv, Tp, filt, Fp, 8192, 8192);
  gemm_deep<false, false><<<256, NTHREADS, 0, stream>>>(wavelets, Fp, nullptr, out, 8192, 8192);
}

// Round 7
// 184.189 us; speedup vs baseline: 1.0729x; 1.0729x over previous
//
#include <hip/hip_runtime.h>
#include <hip/hip_bf16.h>
#include <stdint.h>
#include <stddef.h>

typedef __bf16 bf16;
typedef float f32x4 __attribute__((ext_vector_type(4)));
typedef bf16 bf16x8 __attribute__((ext_vector_type(8)));
typedef bf16 bf16x4 __attribute__((ext_vector_type(4)));

#define MROWS 8192
#define NOUT 256
#define BM 32
#define BK 128      // compute K-step
#define PSTEPS 4    // K-steps per staged panel
#define PK (BK * PSTEPS)  // 512 floats per row per panel
#define NTHREADS 512

#define SLOT_BYTES (BM * PK * 2)      // 32 KiB panel slot (bf16), x2 = 64 KiB
#define LDS_SMALL (BM * BK * 2)       // 8 KiB for the small-K kernel

#define SCHED0 __builtin_amdgcn_sched_barrier(0)
#define SBAR __builtin_amdgcn_s_barrier()

// ---------------------------------------------------------------------------
// Bp fragment-permuted layout (unchanged): for K-step ts, wave w, frag
// (bfi,ak), lane l, 16-byte chunk at byte (ts*64 + w*8 + bfi*4 + ak)*1024 +
// l*16, holding B[n][k0..k0+7], n = w*32+bfi*16+(l&15), k0 = ts*128+ak*32+
// (l>>4)*8.  Producer map for (n,k): ts=k>>7, w=n>>5, bfi=(n>>4)&1,
// ak=(k>>5)&3, l=((k>>3)&3)*16+(n&15), byte=(k&7)*2.
// ---------------------------------------------------------------------------

// ============== panelized big-K kernel (K % 512 == 0) =======================
// A staged in 4-step panels: 32 rows x 2KB contiguous per row per panel
// (DRAM page locality), one barrier per panel (not per step). B register-
// prefetched 1 step ahead from L2-resident Bp. No manual waits inside panels.
template <bool SCALE, bool OUTT>
__global__ __launch_bounds__(NTHREADS, 1) void gemm_big(
    const float* __restrict__ A, const bf16* __restrict__ Bp,
    const float* __restrict__ filt, void* __restrict__ outp,
    const int K, const int lda) {
  __shared__ char lds[2][SLOT_BYTES];
  const int t = threadIdx.x;
  const int w = t >> 6;
  const int l = t & 63;
  const int m0 = blockIdx.x * BM;
  const int NT = K / BK;
  const int NP = K / PK;

  // ---- A staging map: thread -> (row ar, 8-float column group ac).
  // Panel pp, load q (0..7): col = pp*512 + (q>>1)*128 + (q&1)*4 + ac*8.
  const int ar = t >> 4;
  const int ac = t & 15;
  const float* gA = A + (size_t)(m0 + ar) * (size_t)lda + ac * 8;

  // ds_write chunk j (0..3): 16B at row ar, swizzled
  int awoff[4];
#pragma unroll
  for (int j = 0; j < 4; ++j)
    awoff[j] = ar * 2048 / 2 + ((j * 256 + ac * 16) ^ ((ar & 7) << 4));
  // (row stride = PK*2 = 1024 bytes)

  // ---- A fragment read offsets: step s adds s*256 (disjoint bits from XOR)
  int aoff0[2][4];
#pragma unroll
  for (int af = 0; af < 2; ++af)
#pragma unroll
    for (int ak = 0; ak < 4; ++ak) {
      const int r = af * 16 + (l & 15);
      aoff0[af][ak] = r * 1024 + ((ak * 64 + (l >> 4) * 16) ^ ((r & 7) << 4));
    }

  const char* pBw = (const char*)Bp + w * 8192 + l * 16;

  f32x4 acc[2][2] = {};
  f32x4 pA[8];
  bf16x8 Breg[2][2][4];

  // ================= prologue: panel 0 + B(0) =================
#pragma unroll
  for (int q = 0; q < 8; ++q)
    pA[q] = __builtin_nontemporal_load(
        (const f32x4*)(gA + (q >> 1) * 128 + (q & 1) * 4));
#pragma unroll
  for (int bfi = 0; bfi < 2; ++bfi)
#pragma unroll
    for (int ak = 0; ak < 4; ++ak)
      Breg[0][bfi][ak] = *(const bf16x8*)(pBw + (bfi * 4 + ak) * 1024);
#pragma unroll
  for (int j = 0; j < 4; ++j) {
    bf16x8 pk;
#pragma unroll
    for (int e = 0; e < 4; ++e) {
      pk[e] = (bf16)pA[2 * j][e];
      pk[e + 4] = (bf16)pA[2 * j + 1][e];
    }
    *(bf16x8*)(lds[0] + awoff[j]) = pk;
  }
  asm volatile("s_waitcnt lgkmcnt(0)" ::: "memory");
  SBAR;

  // ================= main loop: NP panels x 4 steps =================
  for (int p = 0; p < NP; ++p) {
    const int pn = (p + 1 < NP) ? p + 1 : 0;  // next panel (clamped)
    const char* rslot = lds[p & 1];
    char* wslot = lds[(p + 1) & 1];
    const float* gApn = gA + (size_t)pn * PK;

#pragma unroll
    for (int s = 0; s < PSTEPS; ++s) {
      const int ts = p * PSTEPS + s;
      // B(ts+1) register prefetch (L2-resident, fully coalesced 1KB/wave)
      const size_t kb1 = (size_t)((ts + 1 < NT) ? ts + 1 : 0) << 16;
#pragma unroll
      for (int bfi = 0; bfi < 2; ++bfi)
#pragma unroll
        for (int ak = 0; ak < 4; ++ak)
          Breg[(s + 1) & 1][bfi][ak] =
              *(const bf16x8*)(pBw + kb1 + (bfi * 4 + ak) * 1024);
      SCHED0;
      // A loads for panel p+1: 4 at s=0, 4 at s=1 (>=2 steps of slack;
      // issued AFTER the B group so in-order vmcnt never makes a B-use
      // wait on an A HBM return)
      if (s < 2) {
#pragma unroll
        for (int q4 = 0; q4 < 4; ++q4) {
          const int q = s * 4 + q4;
          pA[q] = __builtin_nontemporal_load(
              (const f32x4*)(gApn + (q >> 1) * 128 + (q & 1) * 4));
        }
        SCHED0;
      }
      // fragments + MFMA (compiler inserts counted lgkmcnt)
      bf16x8 afr[2][4];
#pragma unroll
      for (int af = 0; af < 2; ++af)
#pragma unroll
        for (int ak = 0; ak < 4; ++ak)
          afr[af][ak] = *(const bf16x8*)(rslot + aoff0[af][ak] + s * 256);
      __builtin_amdgcn_s_setprio(1);
#pragma unroll
      for (int ak = 0; ak < 4; ++ak)
#pragma unroll
        for (int af = 0; af < 2; ++af)
#pragma unroll
          for (int bfi = 0; bfi < 2; ++bfi)
            acc[af][bfi] = __builtin_amdgcn_mfma_f32_16x16x32_bf16(
                afr[af][ak], Breg[s & 1][bfi][ak], acc[af][bfi], 0, 0, 0);
      __builtin_amdgcn_s_setprio(0);
    }
    // panel end: cvt + write next panel (compiler inserts vmcnt for pA)
#pragma unroll
    for (int j = 0; j < 4; ++j) {
      bf16x8 pk;
#pragma unroll
      for (int e = 0; e < 4; ++e) {
        pk[e] = (bf16)pA[2 * j][e];
        pk[e + 4] = (bf16)pA[2 * j + 1][e];
      }
      *(bf16x8*)(wslot + awoff[j]) = pk;
    }
    asm volatile("s_waitcnt lgkmcnt(0)" ::: "memory");
    SBAR;
  }

  // ---- epilogue (C/D: col = lane&15, row = (lane>>4)*4 + reg)
#pragma unroll
  for (int af = 0; af < 2; ++af)
#pragma unroll
    for (int bfi = 0; bfi < 2; ++bfi) {
      const int mb = m0 + af * 16 + (l >> 4) * 4;
      const int n = w * 32 + bfi * 16 + (l & 15);
      f32x4 v = acc[af][bfi];
      if (SCALE) {
#pragma unroll
        for (int j = 0; j < 4; ++j) v[j] *= filt[mb + j];
      }
      if (OUTT) {
        bf16x4 pv;
#pragma unroll
        for (int j = 0; j < 4; ++j) pv[j] = (bf16)v[j];
        const int tsq = mb >> 7, wq = n >> 5, bq = (n >> 4) & 1, aq = (mb >> 5) & 3;
        const int lq = ((mb >> 3) & 3) * 16 + (n & 15);
        char* dst = (char*)outp +
                    (size_t)(((tsq * 64 + wq * 8 + bq * 4 + aq) << 10) + lq * 16 +
                             (mb & 7) * 2);
        *(bf16x4*)dst = pv;
      } else {
        float* po = (float*)outp + (size_t)mb * NOUT + n;
#pragma unroll
        for (int j = 0; j < 4; ++j) po[(size_t)j * NOUT] = v[j];
      }
    }
}

// ======================= small-K kernel (round-4 schedule, NT>=2) ===========
template <bool SCALE, bool OUTT>
__global__ __launch_bounds__(NTHREADS, 1) void gemm_small(
    const float* __restrict__ A, const bf16* __restrict__ Bp,
    const float* __restrict__ filt, void* __restrict__ outp,
    const int K, const int lda) {
  __shared__ char lds[2][LDS_SMALL];
  const int t = threadIdx.x;
  const int w = t >> 6;
  const int l = t & 63;
  const int m0 = blockIdx.x * BM;
  const int NT = K / BK;

  const int ar = t >> 4;
  const int acb = t & 15;
  const float* gA = A + (size_t)(m0 + ar) * (size_t)lda + acb * 8;
  const int a_lds_off = (ar * (BK * 2) + acb * 16) ^ ((ar & 7) << 4);

  int aoff[2][4];
#pragma unroll
  for (int af = 0; af < 2; ++af)
#pragma unroll
    for (int ak = 0; ak < 4; ++ak) {
      const int r = af * 16 + (l & 15);
      const int kb = ak * 64 + (l >> 4) * 16;
      aoff[af][ak] = (r * (BK * 2) + kb) ^ ((r & 7) << 4);
    }

  const char* pBw = (const char*)Bp + w * 8192 + l * 16;

  f32x4 acc[2][2] = {};

  f32x4 aS0a = __builtin_nontemporal_load((const f32x4*)gA);
  f32x4 aS0b = __builtin_nontemporal_load((const f32x4*)gA + 1);
  f32x4 aS1a = __builtin_nontemporal_load((const f32x4*)(gA + BK));
  f32x4 aS1b = __builtin_nontemporal_load((const f32x4*)(gA + BK) + 1);
  bf16x8 Bc[2][4], Bn[2][4];
#pragma unroll
  for (int bfi = 0; bfi < 2; ++bfi)
#pragma unroll
    for (int ak = 0; ak < 4; ++ak)
      Bc[bfi][ak] = *(const bf16x8*)(pBw + (bfi * 4 + ak) * 1024);
  {
    bf16x8 pk;
#pragma unroll
    for (int j = 0; j < 4; ++j) { pk[j] = (bf16)aS0a[j]; pk[j + 4] = (bf16)aS0b[j]; }
    *(bf16x8*)(lds[0] + a_lds_off) = pk;
  }
  asm volatile("s_waitcnt lgkmcnt(0)" ::: "memory");
  SBAR;
  SCHED0;

#define BODY_S(TS, P, BCUR, BNXT, AW0, AW1, AL0, AL1)                         \
  {                                                                           \
    const char* bb = lds[P];                                                  \
    bf16x8 afr[2][4];                                                         \
    _Pragma("unroll") for (int af = 0; af < 2; ++af)                          \
        _Pragma("unroll") for (int ak = 0; ak < 4; ++ak)                      \
            afr[af][ak] = *(const bf16x8*)(bb + aoff[af][ak]);                \
    SCHED0;                                                                   \
    const size_t kb1 = (size_t)((((TS) + 1) < NT ? ((TS) + 1) : 0)) << 16;    \
    _Pragma("unroll") for (int bfi = 0; bfi < 2; ++bfi)                       \
        _Pragma("unroll") for (int ak = 0; ak < 4; ++ak)                      \
            BNXT[bfi][ak] =                                                   \
                *(const bf16x8*)(pBw + kb1 + (bfi * 4 + ak) * 1024);          \
    SCHED0;                                                                   \
    const int ka2 = (((TS) + 2) < NT ? ((TS) + 2) : 0) * BK;                  \
    AL0 = __builtin_nontemporal_load((const f32x4*)(gA + ka2));               \
    AL1 = __builtin_nontemporal_load((const f32x4*)(gA + ka2) + 1);           \
    SCHED0;                                                                   \
    asm volatile("s_waitcnt lgkmcnt(0)" ::: "memory");                        \
    SCHED0;                                                                   \
    __builtin_amdgcn_s_setprio(1);                                            \
    _Pragma("unroll") for (int ak = 0; ak < 4; ++ak)                          \
        _Pragma("unroll") for (int af = 0; af < 2; ++af)                      \
            _Pragma("unroll") for (int bfi = 0; bfi < 2; ++bfi)               \
                acc[af][bfi] = __builtin_amdgcn_mfma_f32_16x16x32_bf16(       \
                    afr[af][ak], BCUR[bfi][ak], acc[af][bfi], 0, 0, 0);       \
    __builtin_amdgcn_s_setprio(0);                                            \
    SCHED0;                                                                   \
    {                                                                         \
      bf16x8 pk;                                                              \
      _Pragma("unroll") for (int j = 0; j < 4; ++j) {                         \
        pk[j] = (bf16)AW0[j];                                                 \
        pk[j + 4] = (bf16)AW1[j];                                             \
      }                                                                       \
      *(bf16x8*)(lds[P ^ 1] + a_lds_off) = pk;                                \
    }                                                                         \
    asm volatile("s_waitcnt lgkmcnt(0)" ::: "memory");                        \
    SBAR;                                                                     \
    SCHED0;                                                                   \
  }

  for (int ts = 0; ts < NT; ts += 2) {
    BODY_S(ts, 0, Bc, Bn, aS1a, aS1b, aS0a, aS0b);
    BODY_S(ts + 1, 1, Bn, Bc, aS0a, aS0b, aS1a, aS1b);
  }
#undef BODY_S

#pragma unroll
  for (int af = 0; af < 2; ++af)
#pragma unroll
    for (int bfi = 0; bfi < 2; ++bfi) {
      const int mb = m0 + af * 16 + (l >> 4) * 4;
      const int n = w * 32 + bfi * 16 + (l & 15);
      f32x4 v = acc[af][bfi];
      if (SCALE) {
#pragma unroll
        for (int j = 0; j < 4; ++j) v[j] *= filt[mb + j];
      }
      if (OUTT) {
        bf16x4 pv;
#pragma unroll
        for (int j = 0; j < 4; ++j) pv[j] = (bf16)v[j];
        const int tsq = mb >> 7, wq = n >> 5, bq = (n >> 4) & 1, aq = (mb >> 5) & 3;
        const int lq = ((mb >> 3) & 3) * 16 + (n & 15);
        char* dst = (char*)outp +
                    (size_t)(((tsq * 64 + wq * 8 + bq * 4 + aq) << 10) + lq * 16 +
                             (mb & 7) * 2);
        *(bf16x4*)dst = pv;
      } else {
        float* po = (float*)outp + (size_t)mb * NOUT + n;
#pragma unroll
        for (int j = 0; j < 4; ++j) po[(size_t)j * NOUT] = v[j];
      }
    }
}

// W [256 k][256 n] fp32 -> Wp bf16 in Bp layout
__global__ void prep_wt(const float* __restrict__ W, bf16* __restrict__ Wp) {
  const int k = blockIdx.x;
  const int n = threadIdx.x;
  const int off = (((k >> 7) * 64 + (n >> 5) * 8 + ((n >> 4) & 1) * 4 +
                    ((k >> 5) & 3)) << 10) +
                  (((k >> 3) & 3) * 16 + (n & 15)) * 16 + (k & 7) * 2;
  *(bf16*)((char*)Wp + off) = (bf16)W[k * 256 + n];
}

extern "C" void kernel_launch(void* const* d_in, const int* in_sizes, int n_in,
                              void* d_out, int out_size, void* d_ws, size_t ws_size,
                              hipStream_t stream) {
  const float* features = (const float*)d_in[0];
  const float* wavelets = (const float*)d_in[1];
  const float* wavelets_inv = (const float*)d_in[2];
  const float* W = (const float*)d_in[3];
  const float* filt = (const float*)d_in[4];
  float* out = (float*)d_out;

  char* ws = (char*)d_ws;
  bf16* Wp = (bf16*)ws;                       // 128 KiB, Bp layout (K=256)
  bf16* Tp = (bf16*)(ws + 131072);            // 4 MiB, Bp layout (K=8192)
  bf16* Fp = (bf16*)(ws + 131072 + 4194304);  // 4 MiB, Bp layout (K=8192)

  prep_wt<<<256, 256, 0, stream>>>(W, Wp);
  gemm_small<false, true><<<256, NTHREADS, 0, stream>>>(features, Wp, nullptr, Tp, 256, 256);
  gemm_big<true, true><<<256, NTHREADS, 0, stream>>>(wavelets_inv, Tp, filt, Fp, 8192, 8192);
  gemm_big<false, false><<<256, NTHREADS, 0, stream>>>(wavelets, Fp, nullptr, out, 8192, 8192);
}

// Round 8
// 174.960 us; speedup vs baseline: 1.1294x; 1.0528x over previous
//
#include <hip/hip_runtime.h>
#include <hip/hip_bf16.h>
#include <stdint.h>
#include <stddef.h>

typedef __bf16 bf16;
typedef float f32x4 __attribute__((ext_vector_type(4)));
typedef bf16 bf16x8 __attribute__((ext_vector_type(8)));
typedef bf16 bf16x4 __attribute__((ext_vector_type(4)));

#define MROWS 8192
#define NOUT 256
#define BM 32
#define BK 128      // compute K-step
#define PSTEPS 4    // K-steps per staged panel
#define PK (BK * PSTEPS)  // 512 floats per row per panel
#define NTHREADS 512

#define SLOT_BYTES (BM * PK * 2)      // 32 KiB panel slot (bf16), x2 = 64 KiB
#define LDS_SMALL (BM * BK * 2)       // 8 KiB for the small-K kernel

#define SCHED0 __builtin_amdgcn_sched_barrier(0)
#define SBAR __builtin_amdgcn_s_barrier()

// ---------------------------------------------------------------------------
// Bp fragment-permuted layout (unchanged): for K-step ts, wave w, frag
// (bfi,ak), lane l, 16-byte chunk at byte (ts*64 + w*8 + bfi*4 + ak)*1024 +
// l*16, holding B[n][k0..k0+7], n = w*32+bfi*16+(l&15), k0 = ts*128+ak*32+
// (l>>4)*8.  Producer map for (n,k): ts=k>>7, w=n>>5, bfi=(n>>4)&1,
// ak=(k>>5)&3, l=((k>>3)&3)*16+(n&15), byte=(k&7)*2.
// ---------------------------------------------------------------------------

// ============== panelized big-K kernel (K % 512 == 0) =======================
// A staged in 4-step panels. NEW vs round 7: A ops are wave-contiguous and
// DENSE — wave w, op q reads row w*4+(q>>1), chunk q&1: 64 lanes x 16B = one
// contiguous 1KB burst, so each 64B line is fetched exactly once even with
// nt (no-L2-alloc) loads. Kills the 2x HBM read amplification of the old
// 16B-at-32B-stride op shape.
template <bool SCALE, bool OUTT>
__global__ __launch_bounds__(NTHREADS, 1) void gemm_big(
    const float* __restrict__ A, const bf16* __restrict__ Bp,
    const float* __restrict__ filt, void* __restrict__ outp,
    const int K, const int lda) {
  __shared__ char lds[2][SLOT_BYTES];
  const int t = threadIdx.x;
  const int w = t >> 6;
  const int l = t & 63;
  const int m0 = blockIdx.x * BM;
  const int NT = K / BK;
  const int NP = K / PK;

  // ---- A staging: wave w owns rows w*4..w*4+3. Op q (0..7): row w*4+(q>>1),
  // float col (q&1)*256 + l*4  -> addr = gAw + (q>>1)*lda + c*256 + l*4
  const float* gAw = A + (size_t)(m0 + w * 4) * (size_t)lda + l * 4;

  // ds_write (b64) offsets: element (r, cf) at byte r*1024 + ((cf*2)^((r&7)<<4))
  int awoff[8];
#pragma unroll
  for (int q = 0; q < 8; ++q) {
    const int r = w * 4 + (q >> 1);
    awoff[q] = r * 1024 + ((((q & 1) * 512) + l * 8) ^ ((r & 7) << 4));
  }

  // ---- A fragment read offsets: step s adds s*256 (disjoint bits from XOR)
  int aoff0[2][4];
#pragma unroll
  for (int af = 0; af < 2; ++af)
#pragma unroll
    for (int ak = 0; ak < 4; ++ak) {
      const int r = af * 16 + (l & 15);
      aoff0[af][ak] = r * 1024 + ((ak * 64 + (l >> 4) * 16) ^ ((r & 7) << 4));
    }

  const char* pBw = (const char*)Bp + w * 8192 + l * 16;

  f32x4 acc[2][2] = {};
  f32x4 pA[8];
  bf16x8 Breg[2][2][4];

  // ================= prologue: panel 0 + B(0) =================
#pragma unroll
  for (int q = 0; q < 8; ++q)
    pA[q] = __builtin_nontemporal_load(
        (const f32x4*)(gAw + (size_t)(q >> 1) * lda + (q & 1) * 256));
#pragma unroll
  for (int bfi = 0; bfi < 2; ++bfi)
#pragma unroll
    for (int ak = 0; ak < 4; ++ak)
      Breg[0][bfi][ak] = *(const bf16x8*)(pBw + (bfi * 4 + ak) * 1024);
#pragma unroll
  for (int q = 0; q < 8; ++q) {
    bf16x4 pk;
#pragma unroll
    for (int e = 0; e < 4; ++e) pk[e] = (bf16)pA[q][e];
    *(bf16x4*)(lds[0] + awoff[q]) = pk;
  }
  asm volatile("s_waitcnt lgkmcnt(0)" ::: "memory");
  SBAR;

  // ================= main loop: NP panels x 4 steps =================
  for (int p = 0; p < NP; ++p) {
    const int pn = (p + 1 < NP) ? p + 1 : 0;  // next panel (clamped)
    const char* rslot = lds[p & 1];
    char* wslot = lds[(p + 1) & 1];
    const float* gApn = gAw + (size_t)pn * PK;

#pragma unroll
    for (int s = 0; s < PSTEPS; ++s) {
      const int ts = p * PSTEPS + s;
      // B(ts+1) register prefetch (L2-resident, fully coalesced 1KB/wave)
      const size_t kb1 = (size_t)((ts + 1 < NT) ? ts + 1 : 0) << 16;
#pragma unroll
      for (int bfi = 0; bfi < 2; ++bfi)
#pragma unroll
        for (int ak = 0; ak < 4; ++ak)
          Breg[(s + 1) & 1][bfi][ak] =
              *(const bf16x8*)(pBw + kb1 + (bfi * 4 + ak) * 1024);
      SCHED0;
      // A loads for panel p+1: 4 dense 1KB ops at s=0, 4 at s=1 (>=2 steps
      // of slack; issued AFTER the B group so in-order vmcnt never makes a
      // B-use wait on an A HBM return)
      if (s < 2) {
#pragma unroll
        for (int q4 = 0; q4 < 4; ++q4) {
          const int q = s * 4 + q4;
          pA[q] = __builtin_nontemporal_load(
              (const f32x4*)(gApn + (size_t)(q >> 1) * lda + (q & 1) * 256));
        }
        SCHED0;
      }
      // fragments + MFMA (compiler inserts counted lgkmcnt)
      bf16x8 afr[2][4];
#pragma unroll
      for (int af = 0; af < 2; ++af)
#pragma unroll
        for (int ak = 0; ak < 4; ++ak)
          afr[af][ak] = *(const bf16x8*)(rslot + aoff0[af][ak] + s * 256);
      __builtin_amdgcn_s_setprio(1);
#pragma unroll
      for (int ak = 0; ak < 4; ++ak)
#pragma unroll
        for (int af = 0; af < 2; ++af)
#pragma unroll
          for (int bfi = 0; bfi < 2; ++bfi)
            acc[af][bfi] = __builtin_amdgcn_mfma_f32_16x16x32_bf16(
                afr[af][ak], Breg[s & 1][bfi][ak], acc[af][bfi], 0, 0, 0);
      __builtin_amdgcn_s_setprio(0);
    }
    // panel end: cvt + write next panel (compiler inserts vmcnt for pA)
#pragma unroll
    for (int q = 0; q < 8; ++q) {
      bf16x4 pk;
#pragma unroll
      for (int e = 0; e < 4; ++e) pk[e] = (bf16)pA[q][e];
      *(bf16x4*)(wslot + awoff[q]) = pk;
    }
    asm volatile("s_waitcnt lgkmcnt(0)" ::: "memory");
    SBAR;
  }

  // ---- epilogue (C/D: col = lane&15, row = (lane>>4)*4 + reg)
#pragma unroll
  for (int af = 0; af < 2; ++af)
#pragma unroll
    for (int bfi = 0; bfi < 2; ++bfi) {
      const int mb = m0 + af * 16 + (l >> 4) * 4;
      const int n = w * 32 + bfi * 16 + (l & 15);
      f32x4 v = acc[af][bfi];
      if (SCALE) {
#pragma unroll
        for (int j = 0; j < 4; ++j) v[j] *= filt[mb + j];
      }
      if (OUTT) {
        bf16x4 pv;
#pragma unroll
        for (int j = 0; j < 4; ++j) pv[j] = (bf16)v[j];
        const int tsq = mb >> 7, wq = n >> 5, bq = (n >> 4) & 1, aq = (mb >> 5) & 3;
        const int lq = ((mb >> 3) & 3) * 16 + (n & 15);
        char* dst = (char*)outp +
                    (size_t)(((tsq * 64 + wq * 8 + bq * 4 + aq) << 10) + lq * 16 +
                             (mb & 7) * 2);
        *(bf16x4*)dst = pv;
      } else {
        float* po = (float*)outp + (size_t)mb * NOUT + n;
#pragma unroll
        for (int j = 0; j < 4; ++j) po[(size_t)j * NOUT] = v[j];
      }
    }
}

// ======================= small-K kernel (round-4 schedule, NT>=2) ===========
template <bool SCALE, bool OUTT>
__global__ __launch_bounds__(NTHREADS, 1) void gemm_small(
    const float* __restrict__ A, const bf16* __restrict__ Bp,
    const float* __restrict__ filt, void* __restrict__ outp,
    const int K, const int lda) {
  __shared__ char lds[2][LDS_SMALL];
  const int t = threadIdx.x;
  const int w = t >> 6;
  const int l = t & 63;
  const int m0 = blockIdx.x * BM;
  const int NT = K / BK;

  const int ar = t >> 4;
  const int acb = t & 15;
  const float* gA = A + (size_t)(m0 + ar) * (size_t)lda + acb * 8;
  const int a_lds_off = (ar * (BK * 2) + acb * 16) ^ ((ar & 7) << 4);

  int aoff[2][4];
#pragma unroll
  for (int af = 0; af < 2; ++af)
#pragma unroll
    for (int ak = 0; ak < 4; ++ak) {
      const int r = af * 16 + (l & 15);
      const int kb = ak * 64 + (l >> 4) * 16;
      aoff[af][ak] = (r * (BK * 2) + kb) ^ ((r & 7) << 4);
    }

  const char* pBw = (const char*)Bp + w * 8192 + l * 16;

  f32x4 acc[2][2] = {};

  f32x4 aS0a = __builtin_nontemporal_load((const f32x4*)gA);
  f32x4 aS0b = __builtin_nontemporal_load((const f32x4*)gA + 1);
  f32x4 aS1a = __builtin_nontemporal_load((const f32x4*)(gA + BK));
  f32x4 aS1b = __builtin_nontemporal_load((const f32x4*)(gA + BK) + 1);
  bf16x8 Bc[2][4], Bn[2][4];
#pragma unroll
  for (int bfi = 0; bfi < 2; ++bfi)
#pragma unroll
    for (int ak = 0; ak < 4; ++ak)
      Bc[bfi][ak] = *(const bf16x8*)(pBw + (bfi * 4 + ak) * 1024);
  {
    bf16x8 pk;
#pragma unroll
    for (int j = 0; j < 4; ++j) { pk[j] = (bf16)aS0a[j]; pk[j + 4] = (bf16)aS0b[j]; }
    *(bf16x8*)(lds[0] + a_lds_off) = pk;
  }
  asm volatile("s_waitcnt lgkmcnt(0)" ::: "memory");
  SBAR;
  SCHED0;

#define BODY_S(TS, P, BCUR, BNXT, AW0, AW1, AL0, AL1)                         \
  {                                                                           \
    const char* bb = lds[P];                                                  \
    bf16x8 afr[2][4];                                                         \
    _Pragma("unroll") for (int af = 0; af < 2; ++af)                          \
        _Pragma("unroll") for (int ak = 0; ak < 4; ++ak)                      \
            afr[af][ak] = *(const bf16x8*)(bb + aoff[af][ak]);                \
    SCHED0;                                                                   \
    const size_t kb1 = (size_t)((((TS) + 1) < NT ? ((TS) + 1) : 0)) << 16;    \
    _Pragma("unroll") for (int bfi = 0; bfi < 2; ++bfi)                       \
        _Pragma("unroll") for (int ak = 0; ak < 4; ++ak)                      \
            BNXT[bfi][ak] =                                                   \
                *(const bf16x8*)(pBw + kb1 + (bfi * 4 + ak) * 1024);          \
    SCHED0;                                                                   \
    const int ka2 = (((TS) + 2) < NT ? ((TS) + 2) : 0) * BK;                  \
    AL0 = __builtin_nontemporal_load((const f32x4*)(gA + ka2));               \
    AL1 = __builtin_nontemporal_load((const f32x4*)(gA + ka2) + 1);           \
    SCHED0;                                                                   \
    asm volatile("s_waitcnt lgkmcnt(0)" ::: "memory");                        \
    SCHED0;                                                                   \
    __builtin_amdgcn_s_setprio(1);                                            \
    _Pragma("unroll") for (int ak = 0; ak < 4; ++ak)                          \
        _Pragma("unroll") for (int af = 0; af < 2; ++af)                      \
            _Pragma("unroll") for (int bfi = 0; bfi < 2; ++bfi)               \
                acc[af][bfi] = __builtin_amdgcn_mfma_f32_16x16x32_bf16(       \
                    afr[af][ak], BCUR[bfi][ak], acc[af][bfi], 0, 0, 0);       \
    __builtin_amdgcn_s_setprio(0);                                            \
    SCHED0;                                                                   \
    {                                                                         \
      bf16x8 pk;                                                              \
      _Pragma("unroll") for (int j = 0; j < 4; ++j) {                         \
        pk[j] = (bf16)AW0[j];                                                 \
        pk[j + 4] = (bf16)AW1[j];                                             \
      }                                                                       \
      *(bf16x8*)(lds[P ^ 1] + a_lds_off) = pk;                                \
    }                                                                         \
    asm volatile("s_waitcnt lgkmcnt(0)" ::: "memory");                        \
    SBAR;                                                                     \
    SCHED0;                                                                   \
  }

  for (int ts = 0; ts < NT; ts += 2) {
    BODY_S(ts, 0, Bc, Bn, aS1a, aS1b, aS0a, aS0b);
    BODY_S(ts + 1, 1, Bn, Bc, aS0a, aS0b, aS1a, aS1b);
  }
#undef BODY_S

#pragma unroll
  for (int af = 0; af < 2; ++af)
#pragma unroll
    for (int bfi = 0; bfi < 2; ++bfi) {
      const int mb = m0 + af * 16 + (l >> 4) * 4;
      const int n = w * 32 + bfi * 16 + (l & 15);
      f32x4 v = acc[af][bfi];
      if (SCALE) {
#pragma unroll
        for (int j = 0; j < 4; ++j) v[j] *= filt[mb + j];
      }
      if (OUTT) {
        bf16x4 pv;
#pragma unroll
        for (int j = 0; j < 4; ++j) pv[j] = (bf16)v[j];
        const int tsq = mb >> 7, wq = n >> 5, bq = (n >> 4) & 1, aq = (mb >> 5) & 3;
        const int lq = ((mb >> 3) & 3) * 16 + (n & 15);
        char* dst = (char*)outp +
                    (size_t)(((tsq * 64 + wq * 8 + bq * 4 + aq) << 10) + lq * 16 +
                             (mb & 7) * 2);
        *(bf16x4*)dst = pv;
      } else {
        float* po = (float*)outp + (size_t)mb * NOUT + n;
#pragma unroll
        for (int j = 0; j < 4; ++j) po[(size_t)j * NOUT] = v[j];
      }
    }
}

// W [256 k][256 n] fp32 -> Wp bf16 in Bp layout
__global__ void prep_wt(const float* __restrict__ W, bf16* __restrict__ Wp) {
  const int k = blockIdx.x;
  const int n = threadIdx.x;
  const int off = (((k >> 7) * 64 + (n >> 5) * 8 + ((n >> 4) & 1) * 4 +
                    ((k >> 5) & 3)) << 10) +
                  (((k >> 3) & 3) * 16 + (n & 15)) * 16 + (k & 7) * 2;
  *(bf16*)((char*)Wp + off) = (bf16)W[k * 256 + n];
}

extern "C" void kernel_launch(void* const* d_in, const int* in_sizes, int n_in,
                              void* d_out, int out_size, void* d_ws, size_t ws_size,
                              hipStream_t stream) {
  const float* features = (const float*)d_in[0];
  const float* wavelets = (const float*)d_in[1];
  const float* wavelets_inv = (const float*)d_in[2];
  const float* W = (const float*)d_in[3];
  const float* filt = (const float*)d_in[4];
  float* out = (float*)d_out;

  char* ws = (char*)d_ws;
  bf16* Wp = (bf16*)ws;                       // 128 KiB, Bp layout (K=256)
  bf16* Tp = (bf16*)(ws + 131072);            // 4 MiB, Bp layout (K=8192)
  bf16* Fp = (bf16*)(ws + 131072 + 4194304);  // 4 MiB, Bp layout (K=8192)

  prep_wt<<<256, 256, 0, stream>>>(W, Wp);
  gemm_small<false, true><<<256, NTHREADS, 0, stream>>>(features, Wp, nullptr, Tp, 256, 256);
  gemm_big<true, true><<<256, NTHREADS, 0, stream>>>(wavelets_inv, Tp, filt, Fp, 8192, 8192);
  gemm_big<false, false><<<256, NTHREADS, 0, stream>>>(wavelets, Fp, nullptr, out, 8192, 8192);
}

// Round 9
// 168.873 us; speedup vs baseline: 1.1702x; 1.0360x over previous
//
#include <hip/hip_runtime.h>
#include <hip/hip_bf16.h>
#include <stdint.h>
#include <stddef.h>

typedef __bf16 bf16;
typedef float f32x4 __attribute__((ext_vector_type(4)));
typedef bf16 bf16x8 __attribute__((ext_vector_type(8)));
typedef bf16 bf16x4 __attribute__((ext_vector_type(4)));

#define MROWS 8192
#define NOUT 256
#define BM 32
#define BK 128      // compute K-step
#define PSTEPS 4    // K-steps per staged panel
#define PK (BK * PSTEPS)  // 512 floats per row per panel
#define NTHREADS 512

#define SLOT_BYTES (BM * PK * 2)      // 32 KiB panel slot (bf16), x2 = 64 KiB
#define LDS_SMALL (BM * BK * 2)       // 8 KiB for the small-K kernel

#define SCHED0 __builtin_amdgcn_sched_barrier(0)
#define SBAR __builtin_amdgcn_s_barrier()

// ---------------------------------------------------------------------------
// Bp fragment-permuted layout (unchanged): for K-step ts, wave w, frag
// (bfi,ak), lane l, 16-byte chunk at byte (ts*64 + w*8 + bfi*4 + ak)*1024 +
// l*16, holding B[n][k0..k0+7], n = w*32+bfi*16+(l&15), k0 = ts*128+ak*32+
// (l>>4)*8.  Producer map for (n,k): ts=k>>7, w=n>>5, bfi=(n>>4)&1,
// ak=(k>>5)&3, l=((k>>3)&3)*16+(n&15), byte=(k&7)*2.
// ---------------------------------------------------------------------------

// ============== panelized big-K kernel (K % 512 == 0, NP >= 3) ==============
// vmcnt-decoupled schedule:
//  - B register prefetch depth 2 (Breg[4] rotating): B(ts+2) issued at ts,
//    consumed 2 steps (~3200 cyc >> L2 latency) later -> per-step B wait is
//    a no-op, and (in-order queue) only implies completion of loads that are
//    themselves >=2 steps old.
//  - A panel p+1 ds_written at the START of panel p (slot freed by the p-1
//    barrier), then pA re-issued for panel p+2 -> A's vmcnt wait targets
//    loads 4-7 steps old; ~64KB/CU of A stays in flight across barriers.
template <bool SCALE, bool OUTT>
__global__ __launch_bounds__(NTHREADS, 1) void gemm_big(
    const float* __restrict__ A, const bf16* __restrict__ Bp,
    const float* __restrict__ filt, void* __restrict__ outp,
    const int K, const int lda) {
  __shared__ char lds[2][SLOT_BYTES];
  const int t = threadIdx.x;
  const int w = t >> 6;
  const int l = t & 63;
  const int m0 = blockIdx.x * BM;
  const int NT = K / BK;
  const int NP = K / PK;

  // ---- A staging: wave w owns rows w*4..w*4+3. Op q (0..7): row w*4+(q>>1),
  // float col (q&1)*256 + l*4 (dense 1KB wave burst)
  const float* gAw = A + (size_t)(m0 + w * 4) * (size_t)lda + l * 4;

  // ds_write (b64) offsets: element (r, cf) at byte r*1024 + ((cf*2)^((r&7)<<4))
  int awoff[8];
#pragma unroll
  for (int q = 0; q < 8; ++q) {
    const int r = w * 4 + (q >> 1);
    awoff[q] = r * 1024 + ((((q & 1) * 512) + l * 8) ^ ((r & 7) << 4));
  }

  // ---- A fragment read offsets: step s adds s*256 (disjoint bits from XOR)
  int aoff0[2][4];
#pragma unroll
  for (int af = 0; af < 2; ++af)
#pragma unroll
    for (int ak = 0; ak < 4; ++ak) {
      const int r = af * 16 + (l & 15);
      aoff0[af][ak] = r * 1024 + ((ak * 64 + (l >> 4) * 16) ^ ((r & 7) << 4));
    }

  const char* pBw = (const char*)Bp + w * 8192 + l * 16;

  f32x4 acc[2][2] = {};
  f32x4 pA[8];
  bf16x8 Breg[4][2][4];

  // ================= prologue =================
  // panel 0 -> pA
#pragma unroll
  for (int q = 0; q < 8; ++q)
    pA[q] = __builtin_nontemporal_load(
        (const f32x4*)(gAw + (size_t)(q >> 1) * lda + (q & 1) * 256));
  SCHED0;
  // B(0) -> set0, B(1) -> set1 (issued after A so the cvt's A-wait below
  // does not drain them)
#pragma unroll
  for (int bfi = 0; bfi < 2; ++bfi)
#pragma unroll
    for (int ak = 0; ak < 4; ++ak) {
      Breg[0][bfi][ak] = *(const bf16x8*)(pBw + (bfi * 4 + ak) * 1024);
      Breg[1][bfi][ak] =
          *(const bf16x8*)(pBw + (1 << 16) + (bfi * 4 + ak) * 1024);
    }
  SCHED0;
  // cvt + write panel 0 -> slot 0 (vmcnt waits only the pA loads)
#pragma unroll
  for (int q = 0; q < 8; ++q) {
    bf16x4 pk;
#pragma unroll
    for (int e = 0; e < 4; ++e) pk[e] = (bf16)pA[q][e];
    *(bf16x4*)(lds[0] + awoff[q]) = pk;
  }
  SCHED0;
  // panel 1 -> pA (stays in flight across the barrier)
#pragma unroll
  for (int q = 0; q < 8; ++q)
    pA[q] = __builtin_nontemporal_load(
        (const f32x4*)(gAw + PK + (size_t)(q >> 1) * lda + (q & 1) * 256));
  asm volatile("s_waitcnt lgkmcnt(0)" ::: "memory");
  SBAR;
  SCHED0;

  // ================= main loop: NP panels x 4 steps =================
  for (int p = 0; p < NP; ++p) {
    const char* rslot = lds[p & 1];
    char* wslot = lds[(p + 1) & 1];
    const int pn2 = (p + 2 < NP) ? p + 2 : 0;
    const float* gApn2 = gAw + (size_t)pn2 * PK;

#pragma unroll
    for (int s = 0; s < PSTEPS; ++s) {
      const int ts = p * PSTEPS + s;
      if (s == 0) {
        // write panel p+1 into the slot freed by the p-1 barrier
        // (vmcnt wait here targets pA loads issued at panel p-1 — 4+ steps old)
#pragma unroll
        for (int q = 0; q < 8; ++q) {
          bf16x4 pk;
#pragma unroll
          for (int e = 0; e < 4; ++e) pk[e] = (bf16)pA[q][e];
          *(bf16x4*)(wslot + awoff[q]) = pk;
        }
        SCHED0;
      }
      // B(ts+2) -> Breg[(s+2)&3] (depth-2 prefetch)
      const size_t kb2 = (size_t)((ts + 2 < NT) ? ts + 2 : 0) << 16;
#pragma unroll
      for (int bfi = 0; bfi < 2; ++bfi)
#pragma unroll
        for (int ak = 0; ak < 4; ++ak)
          Breg[(s + 2) & 3][bfi][ak] =
              *(const bf16x8*)(pBw + kb2 + (bfi * 4 + ak) * 1024);
      SCHED0;
      // A loads for panel p+2: 4 dense 1KB ops at s=0, 4 at s=1
      if (s < 2) {
#pragma unroll
        for (int q4 = 0; q4 < 4; ++q4) {
          const int q = s * 4 + q4;
          pA[q] = __builtin_nontemporal_load(
              (const f32x4*)(gApn2 + (size_t)(q >> 1) * lda + (q & 1) * 256));
        }
        SCHED0;
      }
      // fragments + MFMA (consumes Breg[s&3], issued 2 steps ago)
      bf16x8 afr[2][4];
#pragma unroll
      for (int af = 0; af < 2; ++af)
#pragma unroll
        for (int ak = 0; ak < 4; ++ak)
          afr[af][ak] = *(const bf16x8*)(rslot + aoff0[af][ak] + s * 256);
      __builtin_amdgcn_s_setprio(1);
#pragma unroll
      for (int ak = 0; ak < 4; ++ak)
#pragma unroll
        for (int af = 0; af < 2; ++af)
#pragma unroll
          for (int bfi = 0; bfi < 2; ++bfi)
            acc[af][bfi] = __builtin_amdgcn_mfma_f32_16x16x32_bf16(
                afr[af][ak], Breg[s & 3][bfi][ak], acc[af][bfi], 0, 0, 0);
      __builtin_amdgcn_s_setprio(0);
    }
    asm volatile("s_waitcnt lgkmcnt(0)" ::: "memory");
    SBAR;
  }

  // ---- epilogue (C/D: col = lane&15, row = (lane>>4)*4 + reg)
#pragma unroll
  for (int af = 0; af < 2; ++af)
#pragma unroll
    for (int bfi = 0; bfi < 2; ++bfi) {
      const int mb = m0 + af * 16 + (l >> 4) * 4;
      const int n = w * 32 + bfi * 16 + (l & 15);
      f32x4 v = acc[af][bfi];
      if (SCALE) {
#pragma unroll
        for (int j = 0; j < 4; ++j) v[j] *= filt[mb + j];
      }
      if (OUTT) {
        bf16x4 pv;
#pragma unroll
        for (int j = 0; j < 4; ++j) pv[j] = (bf16)v[j];
        const int tsq = mb >> 7, wq = n >> 5, bq = (n >> 4) & 1, aq = (mb >> 5) & 3;
        const int lq = ((mb >> 3) & 3) * 16 + (n & 15);
        char* dst = (char*)outp +
                    (size_t)(((tsq * 64 + wq * 8 + bq * 4 + aq) << 10) + lq * 16 +
                             (mb & 7) * 2);
        *(bf16x4*)dst = pv;
      } else {
        float* po = (float*)outp + (size_t)mb * NOUT + n;
#pragma unroll
        for (int j = 0; j < 4; ++j) po[(size_t)j * NOUT] = v[j];
      }
    }
}

// ======================= small-K kernel (round-4 schedule, NT>=2) ===========
template <bool SCALE, bool OUTT>
__global__ __launch_bounds__(NTHREADS, 1) void gemm_small(
    const float* __restrict__ A, const bf16* __restrict__ Bp,
    const float* __restrict__ filt, void* __restrict__ outp,
    const int K, const int lda) {
  __shared__ char lds[2][LDS_SMALL];
  const int t = threadIdx.x;
  const int w = t >> 6;
  const int l = t & 63;
  const int m0 = blockIdx.x * BM;
  const int NT = K / BK;

  const int ar = t >> 4;
  const int acb = t & 15;
  const float* gA = A + (size_t)(m0 + ar) * (size_t)lda + acb * 8;
  const int a_lds_off = (ar * (BK * 2) + acb * 16) ^ ((ar & 7) << 4);

  int aoff[2][4];
#pragma unroll
  for (int af = 0; af < 2; ++af)
#pragma unroll
    for (int ak = 0; ak < 4; ++ak) {
      const int r = af * 16 + (l & 15);
      const int kb = ak * 64 + (l >> 4) * 16;
      aoff[af][ak] = (r * (BK * 2) + kb) ^ ((r & 7) << 4);
    }

  const char* pBw = (const char*)Bp + w * 8192 + l * 16;

  f32x4 acc[2][2] = {};

  f32x4 aS0a = __builtin_nontemporal_load((const f32x4*)gA);
  f32x4 aS0b = __builtin_nontemporal_load((const f32x4*)gA + 1);
  f32x4 aS1a = __builtin_nontemporal_load((const f32x4*)(gA + BK));
  f32x4 aS1b = __builtin_nontemporal_load((const f32x4*)(gA + BK) + 1);
  bf16x8 Bc[2][4], Bn[2][4];
#pragma unroll
  for (int bfi = 0; bfi < 2; ++bfi)
#pragma unroll
    for (int ak = 0; ak < 4; ++ak)
      Bc[bfi][ak] = *(const bf16x8*)(pBw + (bfi * 4 + ak) * 1024);
  {
    bf16x8 pk;
#pragma unroll
    for (int j = 0; j < 4; ++j) { pk[j] = (bf16)aS0a[j]; pk[j + 4] = (bf16)aS0b[j]; }
    *(bf16x8*)(lds[0] + a_lds_off) = pk;
  }
  asm volatile("s_waitcnt lgkmcnt(0)" ::: "memory");
  SBAR;
  SCHED0;

#define BODY_S(TS, P, BCUR, BNXT, AW0, AW1, AL0, AL1)                         \
  {                                                                           \
    const char* bb = lds[P];                                                  \
    bf16x8 afr[2][4];                                                         \
    _Pragma("unroll") for (int af = 0; af < 2; ++af)                          \
        _Pragma("unroll") for (int ak = 0; ak < 4; ++ak)                      \
            afr[af][ak] = *(const bf16x8*)(bb + aoff[af][ak]);                \
    SCHED0;                                                                   \
    const size_t kb1 = (size_t)((((TS) + 1) < NT ? ((TS) + 1) : 0)) << 16;    \
    _Pragma("unroll") for (int bfi = 0; bfi < 2; ++bfi)                       \
        _Pragma("unroll") for (int ak = 0; ak < 4; ++ak)                      \
            BNXT[bfi][ak] =                                                   \
                *(const bf16x8*)(pBw + kb1 + (bfi * 4 + ak) * 1024);          \
    SCHED0;                                                                   \
    const int ka2 = (((TS) + 2) < NT ? ((TS) + 2) : 0) * BK;                  \
    AL0 = __builtin_nontemporal_load((const f32x4*)(gA + ka2));               \
    AL1 = __builtin_nontemporal_load((const f32x4*)(gA + ka2) + 1);           \
    SCHED0;                                                                   \
    asm volatile("s_waitcnt lgkmcnt(0)" ::: "memory");                        \
    SCHED0;                                                                   \
    __builtin_amdgcn_s_setprio(1);                                            \
    _Pragma("unroll") for (int ak = 0; ak < 4; ++ak)                          \
        _Pragma("unroll") for (int af = 0; af < 2; ++af)                      \
            _Pragma("unroll") for (int bfi = 0; bfi < 2; ++bfi)               \
                acc[af][bfi] = __builtin_amdgcn_mfma_f32_16x16x32_bf16(       \
                    afr[af][ak], BCUR[bfi][ak], acc[af][bfi], 0, 0, 0);       \
    __builtin_amdgcn_s_setprio(0);                                            \
    SCHED0;                                                                   \
    {                                                                         \
      bf16x8 pk;                                                              \
      _Pragma("unroll") for (int j = 0; j < 4; ++j) {                         \
        pk[j] = (bf16)AW0[j];                                                 \
        pk[j + 4] = (bf16)AW1[j];                                             \
      }                                                                       \
      *(bf16x8*)(lds[P ^ 1] + a_lds_off) = pk;                                \
    }                                                                         \
    asm volatile("s_waitcnt lgkmcnt(0)" ::: "memory");                        \
    SBAR;                                                                     \
    SCHED0;                                                                   \
  }

  for (int ts = 0; ts < NT; ts += 2) {
    BODY_S(ts, 0, Bc, Bn, aS1a, aS1b, aS0a, aS0b);
    BODY_S(ts + 1, 1, Bn, Bc, aS0a, aS0b, aS1a, aS1b);
  }
#undef BODY_S

#pragma unroll
  for (int af = 0; af < 2; ++af)
#pragma unroll
    for (int bfi = 0; bfi < 2; ++bfi) {
      const int mb = m0 + af * 16 + (l >> 4) * 4;
      const int n = w * 32 + bfi * 16 + (l & 15);
      f32x4 v = acc[af][bfi];
      if (SCALE) {
#pragma unroll
        for (int j = 0; j < 4; ++j) v[j] *= filt[mb + j];
      }
      if (OUTT) {
        bf16x4 pv;
#pragma unroll
        for (int j = 0; j < 4; ++j) pv[j] = (bf16)v[j];
        const int tsq = mb >> 7, wq = n >> 5, bq = (n >> 4) & 1, aq = (mb >> 5) & 3;
        const int lq = ((mb >> 3) & 3) * 16 + (n & 15);
        char* dst = (char*)outp +
                    (size_t)(((tsq * 64 + wq * 8 + bq * 4 + aq) << 10) + lq * 16 +
                             (mb & 7) * 2);
        *(bf16x4*)dst = pv;
      } else {
        float* po = (float*)outp + (size_t)mb * NOUT + n;
#pragma unroll
        for (int j = 0; j < 4; ++j) po[(size_t)j * NOUT] = v[j];
      }
    }
}

// W [256 k][256 n] fp32 -> Wp bf16 in Bp layout
__global__ void prep_wt(const float* __restrict__ W, bf16* __restrict__ Wp) {
  const int k = blockIdx.x;
  const int n = threadIdx.x;
  const int off = (((k >> 7) * 64 + (n >> 5) * 8 + ((n >> 4) & 1) * 4 +
                    ((k >> 5) & 3)) << 10) +
                  (((k >> 3) & 3) * 16 + (n & 15)) * 16 + (k & 7) * 2;
  *(bf16*)((char*)Wp + off) = (bf16)W[k * 256 + n];
}

extern "C" void kernel_launch(void* const* d_in, const int* in_sizes, int n_in,
                              void* d_out, int out_size, void* d_ws, size_t ws_size,
                              hipStream_t stream) {
  const float* features = (const float*)d_in[0];
  const float* wavelets = (const float*)d_in[1];
  const float* wavelets_inv = (const float*)d_in[2];
  const float* W = (const float*)d_in[3];
  const float* filt = (const float*)d_in[4];
  float* out = (float*)d_out;

  char* ws = (char*)d_ws;
  bf16* Wp = (bf16*)ws;                       // 128 KiB, Bp layout (K=256)
  bf16* Tp = (bf16*)(ws + 131072);            // 4 MiB, Bp layout (K=8192)
  bf16* Fp = (bf16*)(ws + 131072 + 4194304);  // 4 MiB, Bp layout (K=8192)

  prep_wt<<<256, 256, 0, stream>>>(W, Wp);
  gemm_small<false, true><<<256, NTHREADS, 0, stream>>>(features, Wp, nullptr, Tp, 256, 256);
  gemm_big<true, true><<<256, NTHREADS, 0, stream>>>(wavelets_inv, Tp, filt, Fp, 8192, 8192);
  gemm_big<false, false><<<256, NTHREADS, 0, stream>>>(wavelets, Fp, nullptr, out, 8192, 8192);
}